// Round 8
// baseline (122.404 us; speedup 1.0000x reference)
//
#include <hip/hip_runtime.h>

#define IMG_W 512
#define IMG_H 512
#define PLANE_PX (IMG_W * IMG_H)
#define N_ELEMS (48 * PLANE_PX)
#define NT_MAIN 512
#define NBANDS 32               // 16-row bands
#define NBLK (48 * NBANDS)      // 1536 blocks
#define RSTR 528                // uint2 row stride: 16B/128B aligned

// 2*C1 and 2*C2 (the 0.25 scale factors cancel in num/den)
#define C1x2 2.0e-4f
#define C2x2 1.8e-3f

typedef _Float16 h2 __attribute__((ext_vector_type(2)));
typedef _Float16 h8 __attribute__((ext_vector_type(8)));
typedef float f32x2 __attribute__((ext_vector_type(2)));
typedef float f32x4 __attribute__((ext_vector_type(4)));
typedef __fp16 fp16v2 __attribute__((ext_vector_type(2)));

// Packed f16 FMA (v_pk_fma_f16).
__device__ __forceinline__ h2 h2fma(_Float16 w, h2 v, h2 acc) {
    h2 wv = {w, w};
    return __builtin_elementwise_fma(wv, v, acc);
}
__device__ __forceinline__ unsigned int h2bits(h2 v) {
    union { h2 h; unsigned int u; } c; c.h = v; return c.u;
}
// v_cvt_pkrtz_f16_f32 returns __fp16x2; bit-cast to _Float16x2 (same layout).
__device__ __forceinline__ h2 pkrtz(float x, float y) {
    union { fp16v2 f; h2 h; } c;
    c.f = __builtin_amdgcn_cvt_pkrtz(x, y);
    return c.h;
}

__global__ void __launch_bounds__(NT_MAIN, 4) ssim_main(
    const float* __restrict__ img1, const float* __restrict__ img2,
    float* __restrict__ partials)
{
    // FULL-WIDTH 512-col x 16-row band, 512 threads (8 waves), 1 col/thread
    // (R7-verified: kills horizontal staging/conv redundancy; ~35us).
    // Horizontal zero-padding (reference semantics) via 8 zeroed pad-cols
    // each side in LDS. Packed f16: R[row][col] = {(cs,cd),(css,cdd)} uint2,
    // logical col = global col + 8. XOR swizzle: physical = logical ^
    // ((row&7)<<1) -> b128 reads 2-way bank-balanced, pairs stay contiguous.
    __shared__ __align__(16) uint2 R[16 * RSTR];   // 67,584 B -> 2 blocks/CU

    // Gaussian window (f16 taps for vertical conv).
    constexpr _Float16 Gh[11] = {
        (_Float16)0.00102838f, (_Float16)0.00759876f, (_Float16)0.03600077f,
        (_Float16)0.10936070f, (_Float16)0.21300553f, (_Float16)0.26601173f,
        (_Float16)0.21300553f, (_Float16)0.10936070f, (_Float16)0.03600077f,
        (_Float16)0.00759876f, (_Float16)0.00102838f
    };

    const int tid = threadIdx.x;
    const int lane = tid & 63;
    const int wv = tid >> 6;                     // wave [0,8)

    // Work decode + XCD swizzle: XCD (blockIdx&7) owns 6 contiguous planes.
    const int xcd = blockIdx.x & 7;
    const int idx = blockIdx.x >> 3;             // [0,192)
    const int pl = xcd * 6 + idx / NBANDS;
    const int band = idx & (NBANDS - 1);
    const int ty0 = band * 16;
    const float* pa = img1 + (size_t)pl * PLANE_PX;
    const float* pb = img2 + (size_t)pl * PLANE_PX;

    // Zero the pad columns (logical 0..7 and 520..527, swizzled per row).
    if (tid < 16) {
        const int s = (tid & 7) << 1;
        uint2* row = R + tid * RSTR;
#pragma unroll
        for (int k = 0; k < 8; ++k) {
            row[k ^ s] = make_uint2(0u, 0u);
            row[(520 + k) ^ s] = make_uint2(0u, 0u);
        }
    }

    // ================= Phase A: vertical conv, thread = column ==============
    // Each thread stages 26 rows of its column (coalesced across threads),
    // computes 16 output rows via the sliding 11-tap conv (pk_fma, 2 signals
    // per inst), writes 16 uint2 to LDS.
    const int c = tid;                           // global col [0,512)
    const int ry0 = ty0 - 5;
    float av[26], bv[26];
    const bool intY = (ry0 >= 0) && (ry0 + 26 <= IMG_H);     // block-uniform
    if (intY) {
        const float* qa = pa + (size_t)ry0 * IMG_W + c;
        const float* qb = pb + (size_t)ry0 * IMG_W + c;
#pragma unroll
        for (int j = 0; j < 26; ++j) {
            av[j] = qa[j * IMG_W];
            bv[j] = qb[j * IMG_W];
        }
    } else {
#pragma unroll
        for (int j = 0; j < 26; ++j) {
            int ry = ry0 + j;
            int ryc = min(max(ry, 0), IMG_H - 1);
            float rm = ((unsigned)ry < (unsigned)IMG_H) ? 1.f : 0.f;
            av[j] = pa[(size_t)ryc * IMG_W + c] * rm;
            bv[j] = pb[(size_t)ryc * IMG_W + c] * rm;
        }
    }

    h2 asd[16], asq[16];
#pragma unroll
    for (int k = 0; k < 16; ++k) { asd[k] = (h2)(_Float16)0; asq[k] = (h2)(_Float16)0; }
#pragma unroll
    for (int j = 0; j < 26; ++j) {
        // (s,d) packed to f16 in ONE inst (v_cvt_pkrtz_f16_f32).
        h2 sd = pkrtz(av[j] + bv[j], av[j] - bv[j]);
        h2 sq = sd * sd;                         // v_pk_mul_f16
#pragma unroll
        for (int k = 0; k < 16; ++k) {
            int tt = j - k;
            if (tt >= 0 && tt < 11) {            // folds at compile time
                asd[k] = h2fma(Gh[tt], sd, asd[k]);
                asq[k] = h2fma(Gh[tt], sq, asq[k]);
            }
        }
    }
#pragma unroll
    for (int k = 0; k < 16; ++k) {
        const int sc = (8 + c) ^ ((k & 7) << 1); // swizzled physical col
        R[k * RSTR + sc] = make_uint2(h2bits(asd[k]), h2bits(asq[k]));
    }
    __syncthreads();

    // ================= Phase B: horizontal conv via MFMA + SSIM =============
    // D[m][n] = sum_k A[m][k]*B[k][n], one mfma_f32_16x16x32_f16 per signal:
    //   m = out col in 16-group, k = staged col in 32-window, n = row.
    // Window base = logical LDS col ox0 (global ox0-8 via pads), so
    // A[m][k] = G[k-m-3], k-m-3 in [0,10] (verified afh fragment).
    // A (lane l): m = l&15, k = (l>>4)*8 + j  -> constant band frag.
    // B (lane l): n = l&15, k = (l>>4)*8 + j  -> 4x ds_read_b128.
    // All 512x16 outputs valid: zero masks.
    const int nrow = lane & 15;
    const int khi = lane >> 4;
    const int swz = (nrow & 7) << 1;
    const uint2* Rrow = R + nrow * RSTR;

    // Gaussian band A-fragment (symmetric-tap select + 8 shuffles; lanes
    // >= 11 hold 0 so out-of-band taps are 0).
    int sidx = min(lane, 10 - lane);             // < 0 for lane > 10
    unsigned gvb = 0u;
    gvb = (sidx == 0) ? 0x1436u : gvb;           // f16 bits of G[0]
    gvb = (sidx == 1) ? 0x1FC8u : gvb;
    gvb = (sidx == 2) ? 0x289Cu : gvb;
    gvb = (sidx == 3) ? 0x2F00u : gvb;
    gvb = (sidx == 4) ? 0x32D1u : gvb;
    gvb = (sidx == 5) ? 0x3442u : gvb;           // f16 bits of G[5]
    union { h8 h; unsigned u[4]; } af;
#pragma unroll
    for (int w = 0; w < 4; ++w) {
        int t0 = khi * 8 + 2 * w - nrow;
        unsigned lo = (unsigned)__shfl((int)gvb, (t0 - 3) & 63, 64);
        unsigned hi = (unsigned)__shfl((int)gvb, (t0 - 2) & 63, 64);
        af.u[w] = (lo & 0xFFFFu) | (hi << 16);
    }

    const f32x4 z = {0.f, 0.f, 0.f, 0.f};
    f32x2 acc2 = {0.f, 0.f};                     // packed-f32 accumulator
    const f32x2 c1v = {C1x2, C1x2};
    const f32x2 c2v = {C2x2, C2x2};
#pragma unroll
    for (int ii = 0; ii < 4; ++ii) {
        const int ox0 = (wv * 4 + ii) * 16;      // out-col group [0,512) st 16
        const int cb = ox0 + khi * 8;            // logical window col (even)
        const uint4 q0 = *(const uint4*)&Rrow[(cb + 0) ^ swz];
        const uint4 q1 = *(const uint4*)&Rrow[(cb + 2) ^ swz];
        const uint4 q2 = *(const uint4*)&Rrow[(cb + 4) ^ swz];
        const uint4 q3 = *(const uint4*)&Rrow[(cb + 6) ^ swz];

        // De-interleave packed {(s,d),(ss,dd)} into 4 per-signal frags
        // (each u[i] is one v_perm_b32).
        union { h8 h; unsigned u[4]; } fs, fd, fss, fdd;
        fs.u[0]  = (q0.x & 0xFFFFu) | (q0.z << 16);
        fs.u[1]  = (q1.x & 0xFFFFu) | (q1.z << 16);
        fs.u[2]  = (q2.x & 0xFFFFu) | (q2.z << 16);
        fs.u[3]  = (q3.x & 0xFFFFu) | (q3.z << 16);
        fd.u[0]  = (q0.x >> 16) | (q0.z & 0xFFFF0000u);
        fd.u[1]  = (q1.x >> 16) | (q1.z & 0xFFFF0000u);
        fd.u[2]  = (q2.x >> 16) | (q2.z & 0xFFFF0000u);
        fd.u[3]  = (q3.x >> 16) | (q3.z & 0xFFFF0000u);
        fss.u[0] = (q0.y & 0xFFFFu) | (q0.w << 16);
        fss.u[1] = (q1.y & 0xFFFFu) | (q1.w << 16);
        fss.u[2] = (q2.y & 0xFFFFu) | (q2.w << 16);
        fss.u[3] = (q3.y & 0xFFFFu) | (q3.w << 16);
        fdd.u[0] = (q0.y >> 16) | (q0.w & 0xFFFF0000u);
        fdd.u[1] = (q1.y >> 16) | (q1.w & 0xFFFF0000u);
        fdd.u[2] = (q2.y >> 16) | (q2.w & 0xFFFF0000u);
        fdd.u[3] = (q3.y >> 16) | (q3.w & 0xFFFF0000u);

        f32x4 aS  = __builtin_amdgcn_mfma_f32_16x16x32_f16(af.h, fs.h,  z, 0, 0, 0);
        f32x4 aD  = __builtin_amdgcn_mfma_f32_16x16x32_f16(af.h, fd.h,  z, 0, 0, 0);
        f32x4 aSS = __builtin_amdgcn_mfma_f32_16x16x32_f16(af.h, fss.h, z, 0, 0, 0);
        f32x4 aDD = __builtin_amdgcn_mfma_f32_16x16x32_f16(af.h, fdd.h, z, 0, 0, 0);

        // SSIM epilogue, PACKED f32 (v_pk_{mul,add,fma}_f32): 2 px/inst.
        // num/den share the 0.25 factor -> cancelled; constants are 2*C.
#pragma unroll
        for (int h = 0; h < 2; ++h) {
            f32x2 cs  = {aS[2 * h],  aS[2 * h + 1]};
            f32x2 cd  = {aD[2 * h],  aD[2 * h + 1]};
            f32x2 css = {aSS[2 * h], aSS[2 * h + 1]};
            f32x2 cdd = {aDD[2 * h], aDD[2 * h + 1]};
            f32x2 Pq = cs * cs, Qq = cd * cd;
            f32x2 U = Pq - Qq;                   // 4*mu1*mu2
            f32x2 V = Pq + Qq;                   // 2*(mu1^2+mu2^2)
            f32x2 num = (U + c1v) * ((css - cdd) - U + c2v);
            f32x2 den = (V + c1v) * ((css + cdd) - V + c2v);
            f32x2 rr = {__builtin_amdgcn_rcpf(den.x),
                        __builtin_amdgcn_rcpf(den.y)};
            acc2 = __builtin_elementwise_fma(num, rr, acc2);
        }
    }
    float local = acc2.x + acc2.y;

    // ================= Block reduction -> one partial ========================
#pragma unroll
    for (int off = 32; off > 0; off >>= 1) local += __shfl_down(local, off, 64);
    __syncthreads();                             // all R reads done: safe alias
    float* wp = (float*)R;
    if (lane == 0) wp[wv] = local;
    __syncthreads();
    if (tid == 0) {
        float s = 0.f;
#pragma unroll
        for (int w = 0; w < 8; ++w) s += wp[w];
        partials[blockIdx.x] = s;
    }
}

__global__ void ssim_final(const float* __restrict__ partials,
                           float* __restrict__ out)
{
    __shared__ float wp[4];
    const int tid = threadIdx.x;
    const float4* p4 = (const float4*)partials;  // 1536/4 = 384 float4
    float s = 0.f;
    for (int i = tid; i < NBLK / 4; i += 256) {
        float4 v = p4[i];
        s += (v.x + v.y) + (v.z + v.w);
    }
#pragma unroll
    for (int off = 32; off > 0; off >>= 1) s += __shfl_down(s, off, 64);
    if ((tid & 63) == 0) wp[tid >> 6] = s;
    __syncthreads();
    if (tid == 0)
        out[0] = 1.0f - (wp[0] + wp[1] + wp[2] + wp[3]) * (1.0f / (float)N_ELEMS);
}

extern "C" void kernel_launch(void* const* d_in, const int* in_sizes, int n_in,
                              void* d_out, int out_size, void* d_ws, size_t ws_size,
                              hipStream_t stream) {
    const float* img1 = (const float*)d_in[0];
    const float* img2 = (const float*)d_in[1];
    float* out = (float*)d_out;
    float* partials = (float*)d_ws;     // NBLK floats = 6.1 KB

    ssim_main<<<NBLK, NT_MAIN, 0, stream>>>(img1, img2, partials);
    ssim_final<<<1, 256, 0, stream>>>(partials, out);
}